// Round 4
// baseline (237.232 us; speedup 1.0000x reference)
//
#include <hip/hip_runtime.h>

// MLoss: masked box-MSE + face-BCE + background-BCE over [B=2048, N=2704, C=5].
// 221 MB read once -> ~35 us floor at 6.3 TB/s.
//
// R1: coalesced float4 -> padded LDS -> 4-cell units.
// R2: atomic-free two-stage reduction (atomics to one line were a 270 us wall).
// R3: 84 us even with cache-resident inputs => latency-bound; LDS (43.5 KB)
//     capped occupancy at 3 blocks/CU and the stage->barrier->40-scalar-read
//     chain had nothing to hide behind. Fix: element-parallel, LDS-free.
//     Key fact: a float4-aligned group of 4 elements holds <=1 conf element,
//     and every element's cell-conf y[(e/5)*5] is either y[e0 - e0%5] (one
//     L1-hit scalar) or a component of the thread's own y4.

#define BLOCK 256
#define IPT 4                    // float4 groups per thread
#define LOG_CLAMP -100.0f

__device__ __forceinline__ float clogf(float v) {
    return fmaxf(logf(v), LOG_CLAMP);
}

// Stage 1: per-block partials {sum_sq, sum_bce, sum_bg, face_count}.
__global__ __launch_bounds__(BLOCK) void mloss_reduce(
    const float* __restrict__ x, const float* __restrict__ y,
    float4* __restrict__ partials, long long n_groups)
{
    const long long base = (long long)blockIdx.x * (BLOCK * IPT) + threadIdx.x;

    float s_sq = 0.0f, s_bce = 0.0f, s_bg = 0.0f, s_cnt = 0.0f;

    #pragma unroll
    for (int k = 0; k < IPT; ++k) {
        const long long g = base + (long long)k * BLOCK;
        if (g >= n_groups) break;
        const long long e0 = g * 4;
        const int r = (int)(e0 % 5);           // phase of this group vs cell grid

        const float4 x4 = ((const float4*)x)[g];
        const float4 y4 = ((const float4*)y)[g];
        const float  yc = y[e0 - r];           // conf of the cell containing e0 (L1 hit)

        // Conf element of the cell starting inside this group (if any):
        // jc = (5-r)%5; valid (jc<4) for r!=1. For r==0 it's element 0 (== yc).
        const int jc = (5 - r) % 5;
        const float tnext = (jc == 0) ? y4.x : (jc == 1) ? y4.y : (jc == 2) ? y4.z : y4.w;
        const float pconf = (jc == 0) ? x4.x : (jc == 1) ? x4.y : (jc == 2) ? x4.z : x4.w;
        const bool  has_conf = (r != 1);

        // BCE for the (single) conf element of this group.
        const float lp  = clogf(pconf);
        const float l1p = clogf(1.0f - pconf);
        const bool  mc  = tnext > 0.5f;
        s_bce += (has_conf && mc)  ? -(tnext * lp + (1.0f - tnext) * l1p) : 0.0f;
        s_bg  += (has_conf && !mc) ? -l1p : 0.0f;
        s_cnt += (has_conf && mc)  ? 1.0f : 0.0f;

        // Box MSE for the non-conf elements. Element j's cell-conf is yc if
        // r+j<5 (cell started at/before e0), else tnext (cell started inside).
        #define MLOSS_BOX(J, XJ, YJ) do {                                     \
            const int   m  = r + (J);                                         \
            const bool  ic = (m == 0) || (m == 5);                            \
            const float tj = (m >= 5) ? tnext : yc;                           \
            const float d  = (XJ) - (YJ);                                     \
            s_sq += (!ic && tj > 0.5f) ? d * d : 0.0f;                        \
        } while (0)
        MLOSS_BOX(0, x4.x, y4.x);
        MLOSS_BOX(1, x4.y, y4.y);
        MLOSS_BOX(2, x4.z, y4.z);
        MLOSS_BOX(3, x4.w, y4.w);
        #undef MLOSS_BOX
    }

    // Wave-64 butterfly reduce
    #pragma unroll
    for (int off = 32; off > 0; off >>= 1) {
        s_sq  += __shfl_down(s_sq,  off, 64);
        s_bce += __shfl_down(s_bce, off, 64);
        s_bg  += __shfl_down(s_bg,  off, 64);
        s_cnt += __shfl_down(s_cnt, off, 64);
    }

    __shared__ float4 r_part[BLOCK / 64];
    const int wave = threadIdx.x >> 6;
    const int lane = threadIdx.x & 63;
    if (lane == 0) r_part[wave] = make_float4(s_sq, s_bce, s_bg, s_cnt);
    __syncthreads();
    if (threadIdx.x == 0) {
        float4 t0 = r_part[0];
        #pragma unroll
        for (int w = 1; w < BLOCK / 64; ++w) {
            t0.x += r_part[w].x; t0.y += r_part[w].y;
            t0.z += r_part[w].z; t0.w += r_part[w].w;
        }
        partials[blockIdx.x] = t0;   // plain store, distinct address per block
    }
}

// Stage 2: one block reduces per-block partials (double accumulation),
// mops up any tail elements (none for ref shape), computes the scalar.
#define FBLOCK 1024
__global__ __launch_bounds__(FBLOCK) void mloss_final(
    const float4* __restrict__ partials, int n_parts,
    const float* __restrict__ x, const float* __restrict__ y,
    float* __restrict__ out, long long elem_start, long long n_elems,
    long long n_cells)
{
    double s_sq = 0.0, s_bce = 0.0, s_bg = 0.0, s_cnt = 0.0;
    for (int i = threadIdx.x; i < n_parts; i += FBLOCK) {
        const float4 v = partials[i];
        s_sq += (double)v.x; s_bce += (double)v.y;
        s_bg += (double)v.z; s_cnt += (double)v.w;
    }

    #pragma unroll
    for (int off = 32; off > 0; off >>= 1) {
        s_sq  += __shfl_down(s_sq,  off, 64);
        s_bce += __shfl_down(s_bce, off, 64);
        s_bg  += __shfl_down(s_bg,  off, 64);
        s_cnt += __shfl_down(s_cnt, off, 64);
    }

    __shared__ double r[FBLOCK / 64][4];
    const int wave = threadIdx.x >> 6;
    const int lane = threadIdx.x & 63;
    if (lane == 0) { r[wave][0] = s_sq; r[wave][1] = s_bce; r[wave][2] = s_bg; r[wave][3] = s_cnt; }
    __syncthreads();

    if (threadIdx.x == 0) {
        double t_sq = 0.0, t_bce = 0.0, t_bg = 0.0, face = 0.0;
        #pragma unroll
        for (int w = 0; w < FBLOCK / 64; ++w) {
            t_sq += r[w][0]; t_bce += r[w][1]; t_bg += r[w][2]; face += r[w][3];
        }
        // Tail elements not covered by stage-1 float4 groups.
        for (long long e = elem_start; e < n_elems; ++e) {
            const long long m  = e % 5;
            const long long cb = e - m;
            const float t_cell = y[cb];
            const bool  mask   = t_cell > 0.5f;
            if (m == 0) {
                const float p   = x[e];
                const float lp  = clogf(p);
                const float l1p = clogf(1.0f - p);
                if (mask) { t_bce += (double)(-(t_cell * lp + (1.0f - t_cell) * l1p)); face += 1.0; }
                else      { t_bg  += (double)(-l1p); }
            } else if (mask) {
                const float d = x[e] - y[e];
                t_sq += (double)(d * d);
            }
        }
        const double bg    = (double)n_cells - face;
        const double scale = 1.0 + 1.0 / face;
        *out = (float)(scale * t_sq / (face * 4.0) + scale * t_bce / face + t_bg / bg);
    }
}

extern "C" void kernel_launch(void* const* d_in, const int* in_sizes, int n_in,
                              void* d_out, int out_size, void* d_ws, size_t ws_size,
                              hipStream_t stream) {
    const float* x = (const float*)d_in[0];
    const float* y = (const float*)d_in[1];
    float* out = (float*)d_out;
    float4* partials = (float4*)d_ws;

    const long long n_elems  = (long long)in_sizes[0];   // B*N*5
    const long long n_cells  = n_elems / 5;              // B*N
    const long long n_groups = n_elems / 4;              // float4 groups
    const long long covered  = n_groups * 4;             // == n_elems when 4 | n_elems

    const long long gpb    = (long long)BLOCK * IPT;     // groups per block
    const int       blocks = (int)((n_groups + gpb - 1) / gpb);

    mloss_reduce<<<blocks, BLOCK, 0, stream>>>(x, y, partials, n_groups);
    mloss_final<<<1, FBLOCK, 0, stream>>>(partials, blocks, x, y, out,
                                          covered, n_elems, n_cells);
}

// Round 5
// 235.351 us; speedup vs baseline: 1.0080x; 1.0080x over previous
//
#include <hip/hip_runtime.h>

// MLoss: masked box-MSE + face-BCE + background-BCE over [B=2048, N=2704, C=5].
// 221 MB read once -> ~35 us floor at 6.3 TB/s.
//
// R1: coalesced float4 -> padded LDS -> 4-cell units.
// R2: atomic-free two-stage reduction (atomics to one line were a 270 us wall).
// R3: LDS-free element-parallel form; occupancy 20->65%, conflicts -> 0.
// R4: still 84 us, nothing saturated (HBM 16%, VALU 23%, vmem issue ~2%).
//     VGPR=16 => compiler serialized the k-loop into 4 dependent
//     load->wait->consume round-trips (the `break` + tight regs). Fix:
//     batch all 12 loads up-front (full blocks only; tail -> stage 2),
//     one latency exposure per thread, 4x bytes in flight per wave.

#define BLOCK 256
#define IPT 4                    // float4 groups per thread
#define LOG_CLAMP -100.0f

__device__ __forceinline__ float clogf(float v) {
    return fmaxf(logf(v), LOG_CLAMP);
}

// Stage 1: per-block partials {sum_sq, sum_bce, sum_bg, face_count}.
// Grid covers FULL blocks only: every thread owns exactly IPT groups.
__global__ __launch_bounds__(BLOCK) void mloss_reduce(
    const float* __restrict__ x, const float* __restrict__ y,
    float4* __restrict__ partials)
{
    const long long base = (long long)blockIdx.x * (BLOCK * IPT) + threadIdx.x;
    const float4* gx4 = (const float4*)x;
    const float4* gy4 = (const float4*)y;

    // ---- Batched loads: 12 independent global loads, then one wait ----
    float4 vx[IPT], vy[IPT];
    float  vyc[IPT];
    int    vr[IPT];
    #pragma unroll
    for (int k = 0; k < IPT; ++k) {
        const long long g = base + (long long)k * BLOCK;
        const long long e0 = g * 4;
        const int r = (int)(e0 % 5);
        vr[k]  = r;
        vx[k]  = gx4[g];
        vy[k]  = gy4[g];
        vyc[k] = y[e0 - r];          // conf of the cell containing e0 (L1/L2 hit)
    }

    float s_sq = 0.0f, s_bce = 0.0f, s_bg = 0.0f, s_cnt = 0.0f;

    #pragma unroll
    for (int k = 0; k < IPT; ++k) {
        const int    r  = vr[k];
        const float4 x4 = vx[k];
        const float4 y4 = vy[k];
        const float  yc = vyc[k];

        // Conf element of the cell starting inside this group (if any):
        // jc = (5-r)%5; valid (jc<4) for r!=1. For r==0 it's element 0 (== yc).
        const int jc = (5 - r) % 5;
        const float tnext = (jc == 0) ? y4.x : (jc == 1) ? y4.y : (jc == 2) ? y4.z : y4.w;
        const float pconf = (jc == 0) ? x4.x : (jc == 1) ? x4.y : (jc == 2) ? x4.z : x4.w;
        const bool  has_conf = (r != 1);

        // BCE for the (single) conf element of this group.
        const float lp  = clogf(pconf);
        const float l1p = clogf(1.0f - pconf);
        const bool  mc  = tnext > 0.5f;
        s_bce += (has_conf && mc)  ? -(tnext * lp + (1.0f - tnext) * l1p) : 0.0f;
        s_bg  += (has_conf && !mc) ? -l1p : 0.0f;
        s_cnt += (has_conf && mc)  ? 1.0f : 0.0f;

        // Box MSE for the non-conf elements. Element j's cell-conf is yc if
        // r+j<5 (cell started at/before e0), else tnext (cell started inside).
        #define MLOSS_BOX(J, XJ, YJ) do {                                     \
            const int   m  = r + (J);                                         \
            const bool  ic = (m == 0) || (m == 5);                            \
            const float tj = (m >= 5) ? tnext : yc;                           \
            const float d  = (XJ) - (YJ);                                     \
            s_sq += (!ic && tj > 0.5f) ? d * d : 0.0f;                        \
        } while (0)
        MLOSS_BOX(0, x4.x, y4.x);
        MLOSS_BOX(1, x4.y, y4.y);
        MLOSS_BOX(2, x4.z, y4.z);
        MLOSS_BOX(3, x4.w, y4.w);
        #undef MLOSS_BOX
    }

    // ---- Wave-64 butterfly reduce ----
    #pragma unroll
    for (int off = 32; off > 0; off >>= 1) {
        s_sq  += __shfl_down(s_sq,  off, 64);
        s_bce += __shfl_down(s_bce, off, 64);
        s_bg  += __shfl_down(s_bg,  off, 64);
        s_cnt += __shfl_down(s_cnt, off, 64);
    }

    __shared__ float4 r_part[BLOCK / 64];
    const int wave = threadIdx.x >> 6;
    const int lane = threadIdx.x & 63;
    if (lane == 0) r_part[wave] = make_float4(s_sq, s_bce, s_bg, s_cnt);
    __syncthreads();
    if (threadIdx.x == 0) {
        float4 t0 = r_part[0];
        #pragma unroll
        for (int w = 1; w < BLOCK / 64; ++w) {
            t0.x += r_part[w].x; t0.y += r_part[w].y;
            t0.z += r_part[w].z; t0.w += r_part[w].w;
        }
        partials[blockIdx.x] = t0;   // plain store, distinct address per block
    }
}

// Stage 2: one block reduces per-block partials (double accumulation),
// mops up tail elements not covered by full stage-1 blocks, computes scalar.
#define FBLOCK 1024
__global__ __launch_bounds__(FBLOCK) void mloss_final(
    const float4* __restrict__ partials, int n_parts,
    const float* __restrict__ x, const float* __restrict__ y,
    float* __restrict__ out, long long elem_start, long long n_elems,
    long long n_cells)
{
    double s_sq = 0.0, s_bce = 0.0, s_bg = 0.0, s_cnt = 0.0;
    for (int i = threadIdx.x; i < n_parts; i += FBLOCK) {
        const float4 v = partials[i];
        s_sq += (double)v.x; s_bce += (double)v.y;
        s_bg += (double)v.z; s_cnt += (double)v.w;
    }

    #pragma unroll
    for (int off = 32; off > 0; off >>= 1) {
        s_sq  += __shfl_down(s_sq,  off, 64);
        s_bce += __shfl_down(s_bce, off, 64);
        s_bg  += __shfl_down(s_bg,  off, 64);
        s_cnt += __shfl_down(s_cnt, off, 64);
    }

    __shared__ double r[FBLOCK / 64][4];
    const int wave = threadIdx.x >> 6;
    const int lane = threadIdx.x & 63;
    if (lane == 0) { r[wave][0] = s_sq; r[wave][1] = s_bce; r[wave][2] = s_bg; r[wave][3] = s_cnt; }
    __syncthreads();

    if (threadIdx.x == 0) {
        double t_sq = 0.0, t_bce = 0.0, t_bg = 0.0, face = 0.0;
        #pragma unroll
        for (int w = 0; w < FBLOCK / 64; ++w) {
            t_sq += r[w][0]; t_bce += r[w][1]; t_bg += r[w][2]; face += r[w][3];
        }
        // Tail elements not covered by full stage-1 blocks.
        for (long long e = elem_start; e < n_elems; ++e) {
            const long long m  = e % 5;
            const long long cb = e - m;
            const float t_cell = y[cb];
            const bool  mask   = t_cell > 0.5f;
            if (m == 0) {
                const float p   = x[e];
                const float lp  = clogf(p);
                const float l1p = clogf(1.0f - p);
                if (mask) { t_bce += (double)(-(t_cell * lp + (1.0f - t_cell) * l1p)); face += 1.0; }
                else      { t_bg  += (double)(-l1p); }
            } else if (mask) {
                const float d = x[e] - y[e];
                t_sq += (double)(d * d);
            }
        }
        const double bg    = (double)n_cells - face;
        const double scale = 1.0 + 1.0 / face;
        *out = (float)(scale * t_sq / (face * 4.0) + scale * t_bce / face + t_bg / bg);
    }
}

extern "C" void kernel_launch(void* const* d_in, const int* in_sizes, int n_in,
                              void* d_out, int out_size, void* d_ws, size_t ws_size,
                              hipStream_t stream) {
    const float* x = (const float*)d_in[0];
    const float* y = (const float*)d_in[1];
    float* out = (float*)d_out;
    float4* partials = (float4*)d_ws;

    const long long n_elems  = (long long)in_sizes[0];   // B*N*5
    const long long n_cells  = n_elems / 5;              // B*N
    const long long n_groups = n_elems / 4;              // float4 groups

    const long long gpb         = (long long)BLOCK * IPT;      // 1024 groups/block
    const long long full_blocks = n_groups / gpb;              // 6760 for ref shape
    const long long covered     = full_blocks * gpb * 4;       // elements covered

    if (full_blocks > 0)
        mloss_reduce<<<(int)full_blocks, BLOCK, 0, stream>>>(x, y, partials);
    mloss_final<<<1, FBLOCK, 0, stream>>>(partials, (int)full_blocks,
                                          x, y, out, covered, n_elems, n_cells);
}

// Round 7
// 227.479 us; speedup vs baseline: 1.0429x; 1.0346x over previous
//
#include <hip/hip_runtime.h>

// MLoss: masked box-MSE + face-BCE + background-BCE over [B=2048, N=2704, C=5].
// 221 MB read once; measured wall so far: 2.63 TB/s on the L2-fill path.
//
// R2: atomic-free two-stage reduction (atomics to one line were a 270 us wall).
// R3-R5: 82-84 us invariant to occupancy (20-65%), VGPR (16-68), LDS, MLP,
//     and cache residency => bytes-rate-bound. R6 removes the last two
//     non-streaming features: the dependent scalar yc-load stream (replaced
//     by __shfl_up from the neighbor lane's y4 - the cell conf is already in
//     the wave) and cache pollution from read-once x lines (nontemporal).
// R6b: __builtin_nontemporal_load needs a native vector type, not
//     HIP_vector_type -> load via ext_vector_type(4) alias.

#define BLOCK 256
#define TPC 4                    // tiles (256 groups each) per chunk, unrolled
#define LOG_CLAMP -100.0f

typedef float nvec4 __attribute__((ext_vector_type(4)));

__device__ __forceinline__ float clogf(float v) {
    return fmaxf(logf(v), LOG_CLAMP);
}

// Stage 1: grid-stride over chunks; one float4 partial per BLOCK at the end.
// Group g = 4 consecutive elements [4g, 4g+4). Within a chunk, wave lanes own
// consecutive groups, so lane l-1 holds group g-1 (shuffle source for conf).
__global__ __launch_bounds__(BLOCK) void mloss_reduce(
    const float* __restrict__ x, const float* __restrict__ y,
    float4* __restrict__ partials, int n_chunks)
{
    const int lane = threadIdx.x & 63;
    const int wv   = threadIdx.x >> 6;

    const nvec4*  gx4 = (const nvec4*)x;
    const float4* gy4 = (const float4*)y;

    float s_sq = 0.0f, s_bce = 0.0f, s_bg = 0.0f, s_cnt = 0.0f;

    for (int c = blockIdx.x; c < n_chunks; c += gridDim.x) {
        // ---- Batched loads: 8 vector loads (+<=4 one-lane boundary loads) ----
        int    rr[TPC];
        nvec4  x4[TPC];
        float4 y4[TPC];
        float  yc0[TPC];
        #pragma unroll
        for (int k = 0; k < TPC; ++k) {
            const int g  = (c * TPC + k) * 256 + wv * 64 + lane;
            const int e0 = g * 4;
            const int r  = e0 % 5;
            rr[k] = r;
            x4[k] = __builtin_nontemporal_load(&gx4[g]);  // x: read-once, no alloc
            y4[k] = gy4[g];
            // Lane 0 has no in-wave neighbor for the previous group's conf.
            yc0[k] = (lane == 0 && r != 0) ? y[e0 - r] : 0.0f;
        }

        #pragma unroll
        for (int k = 0; k < TPC; ++k) {
            const int    r = rr[k];
            const nvec4  X = x4[k];
            const float4 Y = y4[k];

            // Conf element of the cell starting inside this group (if any):
            // jc = (5-r)%5 < 4 for r != 1.
            const int jc = (5 - r) % 5;
            const float tnext = (jc == 0) ? Y.x : (jc == 1) ? Y.y : (jc == 2) ? Y.z : Y.w;
            const float pconf = (jc == 0) ? X.x : (jc == 1) ? X.y : (jc == 2) ? X.z : X.w;
            const bool  has_conf = (r != 1);

            const float lp  = clogf(pconf);
            const float l1p = clogf(1.0f - pconf);
            const bool  mc  = tnext > 0.5f;
            s_bce += (has_conf && mc)  ? -(tnext * lp + (1.0f - tnext) * l1p) : 0.0f;
            s_bg  += (has_conf && !mc) ? -l1p : 0.0f;
            s_cnt += (has_conf && mc)  ? 1.0f : 0.0f;

            // Conf of the cell containing e0: component (4-r_recv)&3 of lane
            // l-1's Y. Sender (r_s) side: r_recv=(r_s+4)%5 -> comp:
            // r_s=0 -> Y.x, r_s=2 -> Y.w, r_s=3 -> Y.z, r_s=4 -> Y.y (r_s=1 unused).
            const float outv = (r == 0) ? Y.x : (r == 2) ? Y.w : (r == 3) ? Y.z : Y.y;
            float ycp = __shfl_up(outv, 1, 64);
            if (lane == 0) ycp = yc0[k];
            const float yc = (r == 0) ? Y.x : ycp;

            // Box MSE: element j has m=r+j; m==0/5 is a conf element (skip);
            // cell conf is yc for m<5, tnext for m>5.
            #define MLOSS_BOX(J, XJ, YJ) do {                                 \
                const int   m  = r + (J);                                     \
                const bool  ic = (m == 0) || (m == 5);                        \
                const float tj = (m >= 5) ? tnext : yc;                       \
                const float d  = (XJ) - (YJ);                                 \
                s_sq += (!ic && tj > 0.5f) ? d * d : 0.0f;                    \
            } while (0)
            MLOSS_BOX(0, X.x, Y.x);
            MLOSS_BOX(1, X.y, Y.y);
            MLOSS_BOX(2, X.z, Y.z);
            MLOSS_BOX(3, X.w, Y.w);
            #undef MLOSS_BOX
        }
    }

    // ---- Wave-64 butterfly reduce, then cross-wave via LDS ----
    #pragma unroll
    for (int off = 32; off > 0; off >>= 1) {
        s_sq  += __shfl_down(s_sq,  off, 64);
        s_bce += __shfl_down(s_bce, off, 64);
        s_bg  += __shfl_down(s_bg,  off, 64);
        s_cnt += __shfl_down(s_cnt, off, 64);
    }
    __shared__ float4 r_part[BLOCK / 64];
    if (lane == 0) r_part[wv] = make_float4(s_sq, s_bce, s_bg, s_cnt);
    __syncthreads();
    if (threadIdx.x == 0) {
        float4 t0 = r_part[0];
        #pragma unroll
        for (int w = 1; w < BLOCK / 64; ++w) {
            t0.x += r_part[w].x; t0.y += r_part[w].y;
            t0.z += r_part[w].z; t0.w += r_part[w].w;
        }
        partials[blockIdx.x] = t0;
    }
}

// Stage 2: one block reduces per-block partials (double accumulation),
// mops up tail elements not covered by full chunks, computes the scalar.
#define FBLOCK 1024
__global__ __launch_bounds__(FBLOCK) void mloss_final(
    const float4* __restrict__ partials, int n_parts,
    const float* __restrict__ x, const float* __restrict__ y,
    float* __restrict__ out, long long elem_start, long long n_elems,
    long long n_cells)
{
    double s_sq = 0.0, s_bce = 0.0, s_bg = 0.0, s_cnt = 0.0;
    for (int i = threadIdx.x; i < n_parts; i += FBLOCK) {
        const float4 v = partials[i];
        s_sq += (double)v.x; s_bce += (double)v.y;
        s_bg += (double)v.z; s_cnt += (double)v.w;
    }

    #pragma unroll
    for (int off = 32; off > 0; off >>= 1) {
        s_sq  += __shfl_down(s_sq,  off, 64);
        s_bce += __shfl_down(s_bce, off, 64);
        s_bg  += __shfl_down(s_bg,  off, 64);
        s_cnt += __shfl_down(s_cnt, off, 64);
    }

    __shared__ double r[FBLOCK / 64][4];
    const int wave = threadIdx.x >> 6;
    const int lane = threadIdx.x & 63;
    if (lane == 0) { r[wave][0] = s_sq; r[wave][1] = s_bce; r[wave][2] = s_bg; r[wave][3] = s_cnt; }
    __syncthreads();

    if (threadIdx.x == 0) {
        double t_sq = 0.0, t_bce = 0.0, t_bg = 0.0, face = 0.0;
        #pragma unroll
        for (int w = 0; w < FBLOCK / 64; ++w) {
            t_sq += r[w][0]; t_bce += r[w][1]; t_bg += r[w][2]; face += r[w][3];
        }
        for (long long e = elem_start; e < n_elems; ++e) {
            const long long m  = e % 5;
            const float t_cell = y[e - m];
            const bool  mask   = t_cell > 0.5f;
            if (m == 0) {
                const float p   = x[e];
                const float lp  = clogf(p);
                const float l1p = clogf(1.0f - p);
                if (mask) { t_bce += (double)(-(t_cell * lp + (1.0f - t_cell) * l1p)); face += 1.0; }
                else      { t_bg  += (double)(-l1p); }
            } else if (mask) {
                const float d = x[e] - y[e];
                t_sq += (double)(d * d);
            }
        }
        const double bg    = (double)n_cells - face;
        const double scale = 1.0 + 1.0 / face;
        *out = (float)(scale * t_sq / (face * 4.0) + scale * t_bce / face + t_bg / bg);
    }
}

extern "C" void kernel_launch(void* const* d_in, const int* in_sizes, int n_in,
                              void* d_out, int out_size, void* d_ws, size_t ws_size,
                              hipStream_t stream) {
    const float* x = (const float*)d_in[0];
    const float* y = (const float*)d_in[1];
    float* out = (float*)d_out;
    float4* partials = (float4*)d_ws;

    const long long n_elems  = (long long)in_sizes[0];   // B*N*5
    const long long n_cells  = n_elems / 5;              // B*N
    const long long n_groups = n_elems / 4;              // float4 groups
    const long long n_tiles  = n_groups / 256;           // 27040 for ref shape
    const int       n_chunks = (int)(n_tiles / TPC);     // 6760 for ref shape
    const long long covered  = (long long)n_chunks * TPC * 256 * 4;

    const int NB = (n_chunks < 2048) ? (n_chunks > 0 ? n_chunks : 1) : 2048;

    if (n_chunks > 0)
        mloss_reduce<<<NB, BLOCK, 0, stream>>>(x, y, partials, n_chunks);
    mloss_final<<<1, FBLOCK, 0, stream>>>(partials, (n_chunks > 0) ? NB : 0,
                                          x, y, out, covered, n_elems, n_cells);
}